// Round 1
// baseline (459.023 us; speedup 1.0000x reference)
//
#include <hip/hip_runtime.h>
#include <hip/hip_bf16.h>
#include <cstdint>

#define L2E 1.44269504088896340736f
#define LN2 0.69314718055994530942f

__device__ __forceinline__ float fast_sigmoid(float x){
    float e = exp2f(-x * L2E);
    return __builtin_amdgcn_rcpf(1.0f + e);
}
__device__ __forceinline__ float fast_tanh(float x){
    x = fminf(fmaxf(x, -15.0f), 15.0f);
    float e = exp2f(2.0f * x * L2E);
    return (e - 1.0f) * __builtin_amdgcn_rcpf(e + 1.0f);
}

// ---------------------------------------------------------------------------
// Stage 1: xp[s][b][g] (g in [0,1024): fwd gates 0..511, bwd gates 512..1023)
//   xp = embed[ids] @ W_ih^T + b_ih + b_hh   (stored bf16)
// Weight-stationary: thread owns one gate row (128 fp32 in VGPRs),
// X tile (32 tokens x 128) staged in LDS, broadcast-read.
// ---------------------------------------------------------------------------
__global__ __launch_bounds__(256) void k_xproj(
    const int* __restrict__ ids, const float* __restrict__ embed,
    const float* __restrict__ wf, const float* __restrict__ bif, const float* __restrict__ bhf,
    const float* __restrict__ wb, const float* __restrict__ bib, const float* __restrict__ bhb,
    __hip_bfloat16* __restrict__ xp)
{
    __shared__ float4 X[32][32];   // [token][k4]  16KB
    const int tid = threadIdx.x;
    const int mt  = blockIdx.x >> 2;   // token tile (32 tokens each)
    const int gt  = blockIdx.x & 3;    // gate tile (256 gates each)
    const int g   = gt * 256 + tid;

    const float* wrow;
    float bias;
    if (g < 512){ wrow = wf + (size_t)g * 128;        bias = bif[g] + bhf[g]; }
    else        { wrow = wb + (size_t)(g - 512) * 128; bias = bib[g - 512] + bhb[g - 512]; }

    float4 W[32];
#pragma unroll
    for (int k = 0; k < 32; ++k) W[k] = reinterpret_cast<const float4*>(wrow)[k];

    const int m0 = mt * 32;   // token m = s*128 + b
#pragma unroll
    for (int j = 0; j < 4; ++j){
        int flat = j * 256 + tid;
        int row = flat >> 5, c4 = flat & 31;
        int m = m0 + row;
        int s = m >> 7, b = m & 127;
        int id = ids[b * 256 + s];
        X[row][c4] = reinterpret_cast<const float4*>(embed + (size_t)id * 128)[c4];
    }
    __syncthreads();

    for (int ig = 0; ig < 8; ++ig){
        float a0 = bias, a1 = bias, a2 = bias, a3 = bias;
#pragma unroll
        for (int k = 0; k < 32; ++k){
            float4 w  = W[k];
            float4 x0 = X[ig*4+0][k];
            float4 x1 = X[ig*4+1][k];
            float4 x2 = X[ig*4+2][k];
            float4 x3 = X[ig*4+3][k];
            a0 += x0.x*w.x; a0 += x0.y*w.y; a0 += x0.z*w.z; a0 += x0.w*w.w;
            a1 += x1.x*w.x; a1 += x1.y*w.y; a1 += x1.z*w.z; a1 += x1.w*w.w;
            a2 += x2.x*w.x; a2 += x2.y*w.y; a2 += x2.z*w.z; a2 += x2.w*w.w;
            a3 += x3.x*w.x; a3 += x3.y*w.y; a3 += x3.z*w.z; a3 += x3.w*w.w;
        }
        size_t base = (size_t)(m0 + ig*4) * 1024 + g;
        xp[base         ] = __float2bfloat16(a0);
        xp[base + 1024  ] = __float2bfloat16(a1);
        xp[base + 2048  ] = __float2bfloat16(a2);
        xp[base + 3072  ] = __float2bfloat16(a3);
    }
}

// ---------------------------------------------------------------------------
// Stage 2: LSTM scan. One block per (direction, batch). 512 threads, each
// owns gate row tid of W_hh (128 fp32 in VGPRs). h broadcast via LDS.
// ---------------------------------------------------------------------------
__global__ __launch_bounds__(512) void k_scan(
    const __hip_bfloat16* __restrict__ xp,
    const float* __restrict__ whf, const float* __restrict__ whb,
    float* __restrict__ hf, float* __restrict__ hb)
{
    const int tid = threadIdx.x;
    const int dir = blockIdx.x >> 7;
    const int b   = blockIdx.x & 127;
    const float* wh  = dir ? whb : whf;
    float* hout      = dir ? hb  : hf;

    __shared__ __align__(16) float hbuf[128];
    __shared__ __align__(16) float gbuf[512];

    float4 W[32];
#pragma unroll
    for (int k = 0; k < 32; ++k)
        W[k] = reinterpret_cast<const float4*>(wh + (size_t)tid * 128)[k];

    float c = 0.0f;
    if (tid < 128) hbuf[tid] = 0.0f;
    __syncthreads();

    const __hip_bfloat16* xcol = xp + b * 1024 + (dir ? 512 : 0) + tid;
    int s = dir ? 255 : 0;
    const int sstep = dir ? -1 : 1;
    float xv = __bfloat162float(xcol[(size_t)s * 131072]);

    for (int t = 0; t < 256; ++t){
        float xnext = 0.0f;
        if (t < 255) xnext = __bfloat162float(xcol[(size_t)(s + sstep) * 131072]);

        float acc0 = 0.f, acc1 = 0.f, acc2 = 0.f, acc3 = 0.f;
#pragma unroll
        for (int k = 0; k < 32; ++k){
            float4 h4 = reinterpret_cast<const float4*>(hbuf)[k];
            float4 w  = W[k];
            acc0 += h4.x * w.x; acc1 += h4.y * w.y;
            acc2 += h4.z * w.z; acc3 += h4.w * w.w;
        }
        float gate = xv + ((acc0 + acc1) + (acc2 + acc3));
        // gate groups: i [0,128) f [128,256) g [256,384) o [384,512) (wave-uniform)
        float act = (tid < 256 || tid >= 384) ? fast_sigmoid(gate) : fast_tanh(gate);
        gbuf[tid] = act;
        __syncthreads();
        if (tid < 128){
            float iv = gbuf[tid], fv = gbuf[tid + 128];
            float gv = gbuf[tid + 256], ov = gbuf[tid + 384];
            c = fv * c + iv * gv;
            float h = ov * fast_tanh(c);
            hbuf[tid] = h;
            hout[(size_t)s * 16384 + b * 128 + tid] = h;
        }
        __syncthreads();
        xv = xnext;
        s += sstep;
    }
}

// ---------------------------------------------------------------------------
// Stage 3: emissions em[b][s][t] = [h_f,h_b] . w_em[t] + b_em[t]
// Block = 64 tokens (same b, consecutive s). hs tile + w_em staged in LDS.
// ---------------------------------------------------------------------------
__global__ __launch_bounds__(256) void k_em(
    const float* __restrict__ hf, const float* __restrict__ hb,
    const float* __restrict__ w_em, const float* __restrict__ b_em,
    float* __restrict__ em)
{
    __shared__ __align__(16) float HS[64][260];  // [tok][0:128]=hf, [128:256]=hb
    __shared__ __align__(16) float WE[9][260];
    const int tid = threadIdx.x;
    const int u0  = blockIdx.x * 64;   // token u = b*256 + s
    const int b   = u0 >> 8;
    const int s0  = u0 & 255;

#pragma unroll
    for (int j = 0; j < 8; ++j){
        int flat = j * 256 + tid;
        int r = flat >> 5, c4 = flat & 31;
        int s = s0 + r;
        size_t src = (size_t)(s * 128 + b) * 128 + c4 * 4;
        float4 vf = *reinterpret_cast<const float4*>(hf + src);
        float4 vb = *reinterpret_cast<const float4*>(hb + src);
        *reinterpret_cast<float4*>(&HS[r][c4 * 4])       = vf;
        *reinterpret_cast<float4*>(&HS[r][128 + c4 * 4]) = vb;
    }
    for (int j = tid; j < 9 * 256; j += 256){
        int t = j >> 8, k = j & 255;
        WE[t][k] = w_em[j];
    }
    __syncthreads();

    const int tok = tid >> 2, tq = tid & 3;
    const float4* hrow = reinterpret_cast<const float4*>(&HS[tok][0]);
    for (int rep = 0; rep < 3; ++rep){
        if (rep == 2 && tq != 0) break;
        int t = (rep == 0) ? tq : (rep == 1 ? tq + 4 : 8);
        const float4* wrow4 = reinterpret_cast<const float4*>(&WE[t][0]);
        float acc = b_em[t];
#pragma unroll
        for (int k4 = 0; k4 < 64; ++k4){
            float4 h4 = hrow[k4];
            float4 w4 = wrow4[k4];
            acc += h4.x*w4.x; acc += h4.y*w4.y; acc += h4.z*w4.z; acc += h4.w*w4.w;
        }
        em[(size_t)(u0 + tok) * 9 + t] = acc;
    }
}

// ---------------------------------------------------------------------------
// Stage 4: CRF per-batch NLL. 1 wave per b. Gold score via strided lanes;
// forward algorithm: lanes 0..8 hold alpha[j], exp(trans) pre-materialized,
// per-step logsumexp via anchor a0=alpha[0] (no max needed: spreads bounded).
// ---------------------------------------------------------------------------
__global__ __launch_bounds__(64) void k_crf(
    const float* __restrict__ em, const int* __restrict__ tags,
    const float* __restrict__ start_t, const float* __restrict__ end_t,
    const float* __restrict__ trans, float* __restrict__ perb)
{
    const int b = blockIdx.x;
    const int l = threadIdx.x;
    const int base = b * 256;

    // gold path score
    float sc = 0.0f;
    for (int s = l; s < 256; s += 64){
        int tg = tags[base + s];
        sc += em[(size_t)(base + s) * 9 + tg];
        if (s < 255) sc += trans[tg * 9 + tags[base + s + 1]];
    }
#pragma unroll
    for (int off = 32; off > 0; off >>= 1) sc += __shfl_down(sc, off);

    // forward algorithm
    float alpha = -1e30f, endt = 0.0f;
    float m[9];
#pragma unroll
    for (int i = 0; i < 9; ++i) m[i] = 0.0f;
    if (l < 9){
#pragma unroll
        for (int i = 0; i < 9; ++i) m[i] = exp2f(trans[i * 9 + l] * L2E);
        alpha = start_t[l] + em[(size_t)base * 9 + l];
        endt  = end_t[l];
    }
    float emv = (l < 9) ? em[(size_t)(base + 1) * 9 + l] : 0.0f;
    for (int s = 1; s < 256; ++s){
        float emn = (s < 255 && l < 9) ? em[(size_t)(base + s + 1) * 9 + l] : 0.0f;
        float a0 = __shfl(alpha, 0);
        float e  = exp2f((alpha - a0) * L2E);   // lanes>=9 -> 0
        float ssum = 0.0f;
#pragma unroll
        for (int i = 0; i < 9; ++i) ssum += __shfl(e, i) * m[i];
        alpha = a0 + log2f(ssum) * LN2 + emv;
        emv = emn;
    }
    float v  = (l < 9) ? alpha + endt : -1e30f;
    float mx = v;
#pragma unroll
    for (int off = 32; off > 0; off >>= 1) mx = fmaxf(mx, __shfl_xor(mx, off));
    float ex = (l < 9) ? exp2f((v - mx) * L2E) : 0.0f;
#pragma unroll
    for (int off = 32; off > 0; off >>= 1) ex += __shfl_xor(ex, off);
    float logz = mx + log2f(ex) * LN2;
    if (l == 0){
        float score = sc + start_t[tags[base]] + end_t[tags[base + 255]];
        perb[b] = logz - score;
    }
}

__global__ __launch_bounds__(64) void k_final(const float* __restrict__ perb,
                                              float* __restrict__ out)
{
    const int l = threadIdx.x;
    float v = perb[l] + perb[l + 64];
#pragma unroll
    for (int off = 32; off > 0; off >>= 1) v += __shfl_down(v, off);
    if (l == 0) out[0] = v * (1.0f / 128.0f);
}

// ---------------------------------------------------------------------------
extern "C" void kernel_launch(void* const* d_in, const int* in_sizes, int n_in,
                              void* d_out, int out_size, void* d_ws, size_t ws_size,
                              hipStream_t stream)
{
    (void)in_sizes; (void)n_in; (void)out_size; (void)ws_size;
    const int*   ids   = (const int*)d_in[0];
    const int*   tags  = (const int*)d_in[1];
    const float* embed = (const float*)d_in[2];
    const float* wif   = (const float*)d_in[3];
    const float* whf   = (const float*)d_in[4];
    const float* bif   = (const float*)d_in[5];
    const float* bhf   = (const float*)d_in[6];
    const float* wib   = (const float*)d_in[7];
    const float* whb   = (const float*)d_in[8];
    const float* bib   = (const float*)d_in[9];
    const float* bhb   = (const float*)d_in[10];
    const float* w_em  = (const float*)d_in[11];
    const float* b_em  = (const float*)d_in[12];
    const float* st    = (const float*)d_in[13];
    const float* et    = (const float*)d_in[14];
    const float* tr    = (const float*)d_in[15];
    float* out = (float*)d_out;

    char* p = (char*)d_ws;
    __hip_bfloat16* xp = (__hip_bfloat16*)p;                       // 67,108,864 B
    float* hf   = (float*)(p + 67108864);                          // 16,777,216 B
    float* hb   = (float*)(p + 67108864 + 16777216);               // 16,777,216 B
    float* em   = (float*)(p + 67108864 + 2*16777216);             //  1,179,648 B
    float* perb = (float*)(p + 67108864 + 2*16777216 + 1179648);   //        512 B

    k_xproj<<<dim3(4096), dim3(256), 0, stream>>>(ids, embed, wif, bif, bhf,
                                                  wib, bib, bhb, xp);
    k_scan <<<dim3(256),  dim3(512), 0, stream>>>(xp, whf, whb, hf, hb);
    k_em   <<<dim3(512),  dim3(256), 0, stream>>>(hf, hb, w_em, b_em, em);
    k_crf  <<<dim3(128),  dim3(64),  0, stream>>>(em, tags, st, et, tr, perb);
    k_final<<<dim3(1),    dim3(64),  0, stream>>>(perb, out);
}

// Round 2
// 425.983 us; speedup vs baseline: 1.0776x; 1.0776x over previous
//
#include <hip/hip_runtime.h>
#include <hip/hip_bf16.h>
#include <cstdint>

#define L2E 1.44269504088896340736f
#define LN2 0.69314718055994530942f

typedef short bf16x8 __attribute__((ext_vector_type(8)));
typedef float f32x4 __attribute__((ext_vector_type(4)));

__device__ __forceinline__ float fast_sigmoid(float x){
    float e = exp2f(-x * L2E);
    return __builtin_amdgcn_rcpf(1.0f + e);
}
__device__ __forceinline__ float fast_tanh(float x){
    x = fminf(fmaxf(x, -15.0f), 15.0f);
    float e = exp2f(2.0f * x * L2E);
    return (e - 1.0f) * __builtin_amdgcn_rcpf(e + 1.0f);
}
__device__ __forceinline__ float bf2f(short u){
    union { unsigned int i; float f; } v; v.i = ((unsigned int)(unsigned short)u) << 16;
    return v.f;
}
__device__ __forceinline__ short f2bf(float f){
    union { float f; unsigned int i; } v; v.f = f;
    unsigned int r = v.i + 0x7FFF + ((v.i >> 16) & 1);
    return (short)(r >> 16);
}
__device__ __forceinline__ bf16x8 pack2f4(float4 u0, float4 u1){
    bf16x8 r;
    r[0]=f2bf(u0.x); r[1]=f2bf(u0.y); r[2]=f2bf(u0.z); r[3]=f2bf(u0.w);
    r[4]=f2bf(u1.x); r[5]=f2bf(u1.y); r[6]=f2bf(u1.z); r[7]=f2bf(u1.w);
    return r;
}

// ---------------------------------------------------------------------------
// Stage 1 (MFMA): xp2 = embed[ids] @ [wf;wb]^T + biases, bf16, scattered into
// the scan's per-lane fragment order:
//   E(dir,bg,s,ws,c,l,j8) = ((((dir*8+bg)*256+s)*8+ws)*2+c)*512 + l*8 + j8
// where value (s, b=bg*16+br, gate=dir*512+type*128+hd) lands at
//   ws=hd>>4, lane l=(hd&15)|((br>>2)<<4), j8=type*4+(br&3), c=j8>>3 (type>>1).
// Block = one s (128 tokens). 8 waves; wave wx: dir=wx>>2, type=wx&3,
// owns gates type*128..+128 (8 n-tiles). W fragments resident in VGPRs.
// ---------------------------------------------------------------------------
__global__ __launch_bounds__(512, 2) void k_xproj(
    const int* __restrict__ ids, const float* __restrict__ embed,
    const float* __restrict__ wf, const float* __restrict__ bif, const float* __restrict__ bhf,
    const float* __restrict__ wb, const float* __restrict__ bib, const float* __restrict__ bhb,
    short* __restrict__ xp2)
{
    __shared__ __align__(16) short X[128][136];   // 272B row stride, bank-dense
    const int t = threadIdx.x;
    const int s = blockIdx.x;
    const int l = t & 63;
    const int wx = t >> 6;

    // stage embed rows -> X (bf16). token tt = b; 4 threads per token.
    {
        int tt = t >> 2;
        int id = ids[tt * 256 + s];
        const float4* erow = reinterpret_cast<const float4*>(embed + (size_t)id * 128);
#pragma unroll
        for (int it = 0; it < 4; ++it){
            int o = (t & 3) * 4 + it;                 // 8-float octant
            float4 u0 = erow[o * 2], u1 = erow[o * 2 + 1];
            *reinterpret_cast<bf16x8*>(&X[tt][o * 8]) = pack2f4(u0, u1);
        }
    }

    const int dir = wx >> 2, type = wx & 3;
    const float* W  = dir ? wb  : wf;
    const float* bi = dir ? bib : bif;
    const float* bh = dir ? bhb : bhf;

    bf16x8 wfr[8][4];
    float bias[8];
#pragma unroll
    for (int nt = 0; nt < 8; ++nt){
        int grow = type * 128 + nt * 16 + (l & 15);
        bias[nt] = bi[grow] + bh[grow];
        const float* wr = W + (size_t)grow * 128 + (l >> 4) * 8;
#pragma unroll
        for (int kk = 0; kk < 4; ++kk){
            float4 u0 = *reinterpret_cast<const float4*>(wr + kk * 32);
            float4 u1 = *reinterpret_cast<const float4*>(wr + kk * 32 + 4);
            wfr[nt][kk] = pack2f4(u0, u1);
        }
    }
    __syncthreads();

    const int c  = type >> 1;
    const int j4 = (type & 1) * 4;
    for (int ms = 0; ms < 8; ++ms){
        bf16x8 a[4];
#pragma unroll
        for (int kk = 0; kk < 4; ++kk)
            a[kk] = *reinterpret_cast<const bf16x8*>(&X[ms * 16 + (l & 15)][kk * 32 + (l >> 4) * 8]);
        f32x4 acc[8];
#pragma unroll
        for (int nt = 0; nt < 8; ++nt){
            acc[nt][0] = bias[nt]; acc[nt][1] = bias[nt];
            acc[nt][2] = bias[nt]; acc[nt][3] = bias[nt];
        }
#pragma unroll
        for (int kk = 0; kk < 4; ++kk)
#pragma unroll
            for (int nt = 0; nt < 8; ++nt)
                acc[nt] = __builtin_amdgcn_mfma_f32_16x16x32_bf16(a[kk], wfr[nt][kk], acc[nt], 0, 0, 0);
#pragma unroll
        for (int nt = 0; nt < 8; ++nt){
            size_t e = ((((size_t)(dir * 8 + ms) * 256 + s) * 8 + nt) * 2 + c) * 512 + l * 8 + j4;
            short4 pk;
            pk.x = f2bf(acc[nt][0]); pk.y = f2bf(acc[nt][1]);
            pk.z = f2bf(acc[nt][2]); pk.w = f2bf(acc[nt][3]);
            *reinterpret_cast<short4*>(xp2 + e) = pk;
        }
    }
}

// ---------------------------------------------------------------------------
// Stage 2 (MFMA scan): block = (dir, batch-group of 16). 8 waves; wave w owns
// hdims [16w,16w+16) for all 4 gate types -> lane-local c/h update.
// gates[16x512] = h(bf16,LDS) @ W_hh^T(bf16,VGPR) + xp2(prefetched regs).
// h double-buffered in LDS, 272B row stride. One barrier per step.
// ---------------------------------------------------------------------------
__global__ __launch_bounds__(512, 2) void k_scan(
    const short* __restrict__ xp2,
    const float* __restrict__ whf, const float* __restrict__ whb,
    float* __restrict__ hf, float* __restrict__ hb)
{
    __shared__ __align__(16) short hlds[2][16][136];
    const int t = threadIdx.x, l = t & 63, w = t >> 6;
    const int dir = blockIdx.x >> 3, bg = blockIdx.x & 7;
    const float* Wh = dir ? whb : whf;
    float* hout     = dir ? hb  : hf;

    // W_hh B-fragments (resident)
    bf16x8 wfr[4][4];
#pragma unroll
    for (int ty = 0; ty < 4; ++ty){
        int grow = ty * 128 + 16 * w + (l & 15);
        const float* wr = Wh + (size_t)grow * 128 + (l >> 4) * 8;
#pragma unroll
        for (int kk = 0; kk < 4; ++kk){
            float4 u0 = *reinterpret_cast<const float4*>(wr + kk * 32);
            float4 u1 = *reinterpret_cast<const float4*>(wr + kk * 32 + 4);
            wfr[ty][kk] = pack2f4(u0, u1);
        }
    }
    for (int i = t; i < 16 * 136; i += 512)
        hlds[0][i / 136][i % 136] = 0;
    __syncthreads();

    float cst[4] = {0.f, 0.f, 0.f, 0.f};
    const size_t base0 = (size_t)(dir * 8 + bg) * 256;
    int s = dir ? 255 : 0;
    const int sd = dir ? -1 : 1;

    bf16x8 xpv0, xpv1;
    {
        const short* p = xp2 + ((base0 + s) * 8 + w) * 1024 + l * 8;
        xpv0 = *reinterpret_cast<const bf16x8*>(p);
        xpv1 = *reinterpret_cast<const bf16x8*>(p + 512);
    }

    int cur = 0;
    const int hd = 16 * w + (l & 15);
    for (int it = 0; it < 256; ++it){
        bf16x8 xnx0 = xpv0, xnx1 = xpv1;
        if (it < 255){
            const short* p = xp2 + ((base0 + (s + sd)) * 8 + w) * 1024 + l * 8;
            xnx0 = *reinterpret_cast<const bf16x8*>(p);
            xnx1 = *reinterpret_cast<const bf16x8*>(p + 512);
        }

        bf16x8 a[4];
#pragma unroll
        for (int kk = 0; kk < 4; ++kk)
            a[kk] = *reinterpret_cast<const bf16x8*>(&hlds[cur][l & 15][kk * 32 + (l >> 4) * 8]);

        f32x4 acc[4];
        acc[0][0]=bf2f(xpv0[0]); acc[0][1]=bf2f(xpv0[1]); acc[0][2]=bf2f(xpv0[2]); acc[0][3]=bf2f(xpv0[3]);
        acc[1][0]=bf2f(xpv0[4]); acc[1][1]=bf2f(xpv0[5]); acc[1][2]=bf2f(xpv0[6]); acc[1][3]=bf2f(xpv0[7]);
        acc[2][0]=bf2f(xpv1[0]); acc[2][1]=bf2f(xpv1[1]); acc[2][2]=bf2f(xpv1[2]); acc[2][3]=bf2f(xpv1[3]);
        acc[3][0]=bf2f(xpv1[4]); acc[3][1]=bf2f(xpv1[5]); acc[3][2]=bf2f(xpv1[6]); acc[3][3]=bf2f(xpv1[7]);

#pragma unroll
        for (int kk = 0; kk < 4; ++kk)
#pragma unroll
            for (int ty = 0; ty < 4; ++ty)
                acc[ty] = __builtin_amdgcn_mfma_f32_16x16x32_bf16(a[kk], wfr[ty][kk], acc[ty], 0, 0, 0);

#pragma unroll
        for (int r = 0; r < 4; ++r){
            float iv = fast_sigmoid(acc[0][r]);
            float fv = fast_sigmoid(acc[1][r]);
            float gv = fast_tanh  (acc[2][r]);
            float ov = fast_sigmoid(acc[3][r]);
            float cc = fv * cst[r] + iv * gv;
            cst[r] = cc;
            float h = ov * fast_tanh(cc);
            int b = (l >> 4) * 4 + r;
            hlds[cur ^ 1][b][hd] = f2bf(h);
            hout[((size_t)s * 128 + bg * 16 + b) * 128 + hd] = h;
        }
        __syncthreads();
        xpv0 = xnx0; xpv1 = xnx1;
        cur ^= 1;
        s += sd;
    }
}

// ---------------------------------------------------------------------------
// Stage 3: emissions em[b][s][t] = [h_f,h_b] . w_em[t] + b_em[t]
// ---------------------------------------------------------------------------
__global__ __launch_bounds__(256) void k_em(
    const float* __restrict__ hf, const float* __restrict__ hb,
    const float* __restrict__ w_em, const float* __restrict__ b_em,
    float* __restrict__ em)
{
    __shared__ __align__(16) float HS[64][260];
    __shared__ __align__(16) float WE[9][260];
    const int tid = threadIdx.x;
    const int u0  = blockIdx.x * 64;
    const int b   = u0 >> 8;
    const int s0  = u0 & 255;

#pragma unroll
    for (int j = 0; j < 8; ++j){
        int flat = j * 256 + tid;
        int r = flat >> 5, c4 = flat & 31;
        int s = s0 + r;
        size_t src = (size_t)(s * 128 + b) * 128 + c4 * 4;
        float4 vf = *reinterpret_cast<const float4*>(hf + src);
        float4 vb = *reinterpret_cast<const float4*>(hb + src);
        *reinterpret_cast<float4*>(&HS[r][c4 * 4])       = vf;
        *reinterpret_cast<float4*>(&HS[r][128 + c4 * 4]) = vb;
    }
    for (int j = tid; j < 9 * 256; j += 256){
        int t = j >> 8, k = j & 255;
        WE[t][k] = w_em[j];
    }
    __syncthreads();

    const int tok = tid >> 2, tq = tid & 3;
    const float4* hrow = reinterpret_cast<const float4*>(&HS[tok][0]);
    for (int rep = 0; rep < 3; ++rep){
        if (rep == 2 && tq != 0) break;
        int t = (rep == 0) ? tq : (rep == 1 ? tq + 4 : 8);
        const float4* wrow4 = reinterpret_cast<const float4*>(&WE[t][0]);
        float acc = b_em[t];
#pragma unroll
        for (int k4 = 0; k4 < 64; ++k4){
            float4 h4 = hrow[k4];
            float4 w4 = wrow4[k4];
            acc += h4.x*w4.x; acc += h4.y*w4.y; acc += h4.z*w4.z; acc += h4.w*w4.w;
        }
        em[(size_t)(u0 + tok) * 9 + t] = acc;
    }
}

// ---------------------------------------------------------------------------
// Stage 4: CRF per-batch NLL (1 wave per b), then mean.
// ---------------------------------------------------------------------------
__global__ __launch_bounds__(64) void k_crf(
    const float* __restrict__ em, const int* __restrict__ tags,
    const float* __restrict__ start_t, const float* __restrict__ end_t,
    const float* __restrict__ trans, float* __restrict__ perb)
{
    const int b = blockIdx.x;
    const int l = threadIdx.x;
    const int base = b * 256;

    float sc = 0.0f;
    for (int s = l; s < 256; s += 64){
        int tg = tags[base + s];
        sc += em[(size_t)(base + s) * 9 + tg];
        if (s < 255) sc += trans[tg * 9 + tags[base + s + 1]];
    }
#pragma unroll
    for (int off = 32; off > 0; off >>= 1) sc += __shfl_down(sc, off);

    float alpha = -1e30f, endt = 0.0f;
    float m[9];
#pragma unroll
    for (int i = 0; i < 9; ++i) m[i] = 0.0f;
    if (l < 9){
#pragma unroll
        for (int i = 0; i < 9; ++i) m[i] = exp2f(trans[i * 9 + l] * L2E);
        alpha = start_t[l] + em[(size_t)base * 9 + l];
        endt  = end_t[l];
    }
    float emv = (l < 9) ? em[(size_t)(base + 1) * 9 + l] : 0.0f;
    for (int s = 1; s < 256; ++s){
        float emn = (s < 255 && l < 9) ? em[(size_t)(base + s + 1) * 9 + l] : 0.0f;
        float a0 = __shfl(alpha, 0);
        float e  = exp2f((alpha - a0) * L2E);
        float ssum = 0.0f;
#pragma unroll
        for (int i = 0; i < 9; ++i) ssum += __shfl(e, i) * m[i];
        alpha = a0 + log2f(ssum) * LN2 + emv;
        emv = emn;
    }
    float v  = (l < 9) ? alpha + endt : -1e30f;
    float mx = v;
#pragma unroll
    for (int off = 32; off > 0; off >>= 1) mx = fmaxf(mx, __shfl_xor(mx, off));
    float ex = (l < 9) ? exp2f((v - mx) * L2E) : 0.0f;
#pragma unroll
    for (int off = 32; off > 0; off >>= 1) ex += __shfl_xor(ex, off);
    float logz = mx + log2f(ex) * LN2;
    if (l == 0){
        float score = sc + start_t[tags[base]] + end_t[tags[base + 255]];
        perb[b] = logz - score;
    }
}

__global__ __launch_bounds__(64) void k_final(const float* __restrict__ perb,
                                              float* __restrict__ out)
{
    const int l = threadIdx.x;
    float v = perb[l] + perb[l + 64];
#pragma unroll
    for (int off = 32; off > 0; off >>= 1) v += __shfl_down(v, off);
    if (l == 0) out[0] = v * (1.0f / 128.0f);
}

// ---------------------------------------------------------------------------
extern "C" void kernel_launch(void* const* d_in, const int* in_sizes, int n_in,
                              void* d_out, int out_size, void* d_ws, size_t ws_size,
                              hipStream_t stream)
{
    (void)in_sizes; (void)n_in; (void)out_size; (void)ws_size;
    const int*   ids   = (const int*)d_in[0];
    const int*   tags  = (const int*)d_in[1];
    const float* embed = (const float*)d_in[2];
    const float* wif   = (const float*)d_in[3];
    const float* whf   = (const float*)d_in[4];
    const float* bif   = (const float*)d_in[5];
    const float* bhf   = (const float*)d_in[6];
    const float* wib   = (const float*)d_in[7];
    const float* whb   = (const float*)d_in[8];
    const float* bib   = (const float*)d_in[9];
    const float* bhb   = (const float*)d_in[10];
    const float* w_em  = (const float*)d_in[11];
    const float* b_em  = (const float*)d_in[12];
    const float* st    = (const float*)d_in[13];
    const float* et    = (const float*)d_in[14];
    const float* tr    = (const float*)d_in[15];
    float* out = (float*)d_out;

    char* p = (char*)d_ws;
    short* xp2  = (short*)p;                                       // 67,108,864 B
    float* hf   = (float*)(p + 67108864);                          // 16,777,216 B
    float* hb   = (float*)(p + 83886080);                          // 16,777,216 B
    float* em   = (float*)(p + 100663296);                         //  1,179,648 B
    float* perb = (float*)(p + 101842944);                         //        512 B

    k_xproj<<<dim3(256), dim3(512), 0, stream>>>(ids, embed, wif, bif, bhf,
                                                 wib, bib, bhb, xp2);
    k_scan <<<dim3(16),  dim3(512), 0, stream>>>(xp2, whf, whb, hf, hb);
    k_em   <<<dim3(512), dim3(256), 0, stream>>>(hf, hb, w_em, b_em, em);
    k_crf  <<<dim3(128), dim3(64),  0, stream>>>(em, tags, st, et, tr, perb);
    k_final<<<dim3(1),   dim3(64),  0, stream>>>(perb, out);
}

// Round 3
// 422.106 us; speedup vs baseline: 1.0875x; 1.0092x over previous
//
#include <hip/hip_runtime.h>
#include <hip/hip_bf16.h>
#include <cstdint>

#define L2E 1.44269504088896340736f
#define LN2 0.69314718055994530942f

typedef short bf16x8 __attribute__((ext_vector_type(8)));
typedef float f32x4 __attribute__((ext_vector_type(4)));

__device__ __forceinline__ float fast_sigmoid(float x){
    float e = exp2f(-x * L2E);
    return __builtin_amdgcn_rcpf(1.0f + e);
}
__device__ __forceinline__ float fast_tanh(float x){
    x = fminf(fmaxf(x, -15.0f), 15.0f);
    float e = exp2f(2.0f * x * L2E);
    return (e - 1.0f) * __builtin_amdgcn_rcpf(e + 1.0f);
}
__device__ __forceinline__ float bf2f(short u){
    union { unsigned int i; float f; } v; v.i = ((unsigned int)(unsigned short)u) << 16;
    return v.f;
}
__device__ __forceinline__ short f2bf(float f){
    union { float f; unsigned int i; } v; v.f = f;
    unsigned int r = v.i + 0x7FFF + ((v.i >> 16) & 1);
    return (short)(r >> 16);
}
__device__ __forceinline__ bf16x8 pack2f4(float4 u0, float4 u1){
    bf16x8 r;
    r[0]=f2bf(u0.x); r[1]=f2bf(u0.y); r[2]=f2bf(u0.z); r[3]=f2bf(u0.w);
    r[4]=f2bf(u1.x); r[5]=f2bf(u1.y); r[6]=f2bf(u1.z); r[7]=f2bf(u1.w);
    return r;
}

// ---------------------------------------------------------------------------
// Stage 1 (MFMA): xp2 = embed[ids] @ [wf;wb]^T + biases, bf16, scattered into
// the scan's per-lane fragment order:
//   E(dir,bg,s,nt,c,l,j8) = ((((dir*8+bg)*256+s)*8+nt)*2+c)*512 + l*8 + j8
// Wave = (dir, c, nh): computes BOTH gate types of c-half for nt=nh*4..+4
//   -> one coalesced 16B short8 store per (ms,nt). 32 MFMA/wave/ms.
// ---------------------------------------------------------------------------
__global__ __launch_bounds__(512, 2) void k_xproj(
    const int* __restrict__ ids, const float* __restrict__ embed,
    const float* __restrict__ wf, const float* __restrict__ bif, const float* __restrict__ bhf,
    const float* __restrict__ wb, const float* __restrict__ bib, const float* __restrict__ bhb,
    short* __restrict__ xp2)
{
    __shared__ __align__(16) short X[128][136];   // 272B row stride
    const int t = threadIdx.x;
    const int s = blockIdx.x;
    const int l = t & 63;
    const int wx = t >> 6;
    const int a15 = l & 15, g4 = l >> 4;

    // stage embed rows -> X (bf16). token tt = b; 4 threads per token.
    {
        int tt = t >> 2;
        int id = ids[tt * 256 + s];
        const float4* erow = reinterpret_cast<const float4*>(embed + (size_t)id * 128);
#pragma unroll
        for (int it = 0; it < 4; ++it){
            int o = (t & 3) * 4 + it;
            float4 u0 = erow[o * 2], u1 = erow[o * 2 + 1];
            *reinterpret_cast<bf16x8*>(&X[tt][o * 8]) = pack2f4(u0, u1);
        }
    }

    const int dir = wx >> 2, c = (wx >> 1) & 1, nh = wx & 1;
    const float* W  = dir ? wb  : wf;
    const float* bi = dir ? bib : bif;
    const float* bh = dir ? bhb : bhf;

    bf16x8 wfr[2][4][4];
    float bias[2][4];
#pragma unroll
    for (int j = 0; j < 2; ++j){
        int type = c * 2 + j;
#pragma unroll
        for (int nt = 0; nt < 4; ++nt){
            int grow = type * 128 + (nh * 4 + nt) * 16 + a15;
            bias[j][nt] = bi[grow] + bh[grow];
            const float* wr = W + (size_t)grow * 128 + g4 * 8;
#pragma unroll
            for (int kk = 0; kk < 4; ++kk){
                float4 u0 = *reinterpret_cast<const float4*>(wr + kk * 32);
                float4 u1 = *reinterpret_cast<const float4*>(wr + kk * 32 + 4);
                wfr[j][nt][kk] = pack2f4(u0, u1);
            }
        }
    }
    __syncthreads();

    for (int ms = 0; ms < 8; ++ms){
        bf16x8 a[4];
#pragma unroll
        for (int kk = 0; kk < 4; ++kk)
            a[kk] = *reinterpret_cast<const bf16x8*>(&X[ms * 16 + a15][kk * 32 + g4 * 8]);
        f32x4 acc[2][4];
#pragma unroll
        for (int j = 0; j < 2; ++j)
#pragma unroll
            for (int nt = 0; nt < 4; ++nt){
                acc[j][nt][0] = bias[j][nt]; acc[j][nt][1] = bias[j][nt];
                acc[j][nt][2] = bias[j][nt]; acc[j][nt][3] = bias[j][nt];
            }
#pragma unroll
        for (int kk = 0; kk < 4; ++kk)
#pragma unroll
            for (int j = 0; j < 2; ++j)
#pragma unroll
                for (int nt = 0; nt < 4; ++nt)
                    acc[j][nt] = __builtin_amdgcn_mfma_f32_16x16x32_bf16(a[kk], wfr[j][nt][kk], acc[j][nt], 0, 0, 0);
#pragma unroll
        for (int nt = 0; nt < 4; ++nt){
            size_t e = ((((size_t)(dir * 8 + ms) * 256 + s) * 8 + (nh * 4 + nt)) * 2 + c) * 512 + l * 8;
            bf16x8 pk;
            pk[0]=f2bf(acc[0][nt][0]); pk[1]=f2bf(acc[0][nt][1]);
            pk[2]=f2bf(acc[0][nt][2]); pk[3]=f2bf(acc[0][nt][3]);
            pk[4]=f2bf(acc[1][nt][0]); pk[5]=f2bf(acc[1][nt][1]);
            pk[6]=f2bf(acc[1][nt][2]); pk[7]=f2bf(acc[1][nt][3]);
            *reinterpret_cast<bf16x8*>(xp2 + e) = pk;
        }
    }
}

// ---------------------------------------------------------------------------
// Stage 2 (MFMA scan): block = (dir, batch-group of 16). 8 waves; wave w owns
// hdims [16w,16w+16) x 4 gate types -> lane-local c/h update.
// Deep prefetch: two 4-step register windows (A/B), fully unrolled, so the
// vmcnt(0) drain at each __syncthreads finds loads already complete.
// h global stores issued AFTER the barrier -> retire during the next step.
// ---------------------------------------------------------------------------
__global__ __launch_bounds__(512, 2) void k_scan(
    const short* __restrict__ xp2,
    const float* __restrict__ whf, const float* __restrict__ whb,
    short* __restrict__ hf, short* __restrict__ hb)
{
    __shared__ __align__(16) short hlds[2][16][136];
    const int t = threadIdx.x, l = t & 63, w = t >> 6;
    const int dir = blockIdx.x >> 3, bg = blockIdx.x & 7;
    const float* Wh = dir ? whb : whf;
    short* hout     = dir ? hb  : hf;
    const int a15 = l & 15, g4 = l >> 4;

    // xp addressing (linear time index tt: s = dir ? 255-tt : tt)
    const size_t base0 = (size_t)(dir * 8 + bg) * 256;
    const short* xbase = xp2 + base0 * 8192 + (size_t)(dir ? 255 : 0) * 8192 + w * 1024 + l * 8;
    const long xstep = dir ? -8192L : 8192L;

    // W_hh B-fragments (resident, 64 VGPR)
    bf16x8 wfr[4][4];
#pragma unroll
    for (int ty = 0; ty < 4; ++ty){
        int grow = ty * 128 + 16 * w + a15;
        const float* wr = Wh + (size_t)grow * 128 + g4 * 8;
#pragma unroll
        for (int kk = 0; kk < 4; ++kk){
            float4 u0 = *reinterpret_cast<const float4*>(wr + kk * 32);
            float4 u1 = *reinterpret_cast<const float4*>(wr + kk * 32 + 4);
            wfr[ty][kk] = pack2f4(u0, u1);
        }
    }

#define LDX(D0, D1, TT) do { \
        int tc_ = (TT) & 255; \
        const short* p_ = xbase + (long)tc_ * xstep; \
        D0 = *reinterpret_cast<const bf16x8*>(p_); \
        D1 = *reinterpret_cast<const bf16x8*>(p_ + 512); \
    } while(0)

    // prologue: window A <- t = 0..3
    bf16x8 A00,A01,A10,A11,A20,A21,A30,A31;
    bf16x8 B00,B01,B10,B11,B20,B21,B30,B31;
    LDX(A00,A01,0); LDX(A10,A11,1); LDX(A20,A21,2); LDX(A30,A31,3);

    for (int i = t; i < 2 * 16 * 136; i += 512)
        (&hlds[0][0][0])[i] = 0;
    __syncthreads();

    float c0 = 0.f, c1 = 0.f, c2 = 0.f, c3 = 0.f;
    const short* hr = &hlds[0][a15][g4 * 8];           // + RB*2176 + kk*32
    short* hw0      = &hlds[0][g4 * 4][16 * w + a15];  // + WB*2176 + r*136
    const int hboff = (bg * 16 + g4 * 4) * 128 + 16 * w + a15;
    short* houtbase = hout + (size_t)(dir ? 255 : 0) * 16384 + hboff;
    const long hstep = dir ? -16384L : 16384L;

#define STEPX(XV0, XV1, TT, RB) do { \
        bf16x8 a0_ = *reinterpret_cast<const bf16x8*>(hr + (RB)*2176); \
        bf16x8 a1_ = *reinterpret_cast<const bf16x8*>(hr + (RB)*2176 + 32); \
        bf16x8 a2_ = *reinterpret_cast<const bf16x8*>(hr + (RB)*2176 + 64); \
        bf16x8 a3_ = *reinterpret_cast<const bf16x8*>(hr + (RB)*2176 + 96); \
        f32x4 ac0, ac1, ac2, ac3; \
        ac0[0]=bf2f((XV0)[0]); ac0[1]=bf2f((XV0)[1]); ac0[2]=bf2f((XV0)[2]); ac0[3]=bf2f((XV0)[3]); \
        ac1[0]=bf2f((XV0)[4]); ac1[1]=bf2f((XV0)[5]); ac1[2]=bf2f((XV0)[6]); ac1[3]=bf2f((XV0)[7]); \
        ac2[0]=bf2f((XV1)[0]); ac2[1]=bf2f((XV1)[1]); ac2[2]=bf2f((XV1)[2]); ac2[3]=bf2f((XV1)[3]); \
        ac3[0]=bf2f((XV1)[4]); ac3[1]=bf2f((XV1)[5]); ac3[2]=bf2f((XV1)[6]); ac3[3]=bf2f((XV1)[7]); \
        ac0 = __builtin_amdgcn_mfma_f32_16x16x32_bf16(a0_, wfr[0][0], ac0, 0,0,0); \
        ac1 = __builtin_amdgcn_mfma_f32_16x16x32_bf16(a0_, wfr[1][0], ac1, 0,0,0); \
        ac2 = __builtin_amdgcn_mfma_f32_16x16x32_bf16(a0_, wfr[2][0], ac2, 0,0,0); \
        ac3 = __builtin_amdgcn_mfma_f32_16x16x32_bf16(a0_, wfr[3][0], ac3, 0,0,0); \
        ac0 = __builtin_amdgcn_mfma_f32_16x16x32_bf16(a1_, wfr[0][1], ac0, 0,0,0); \
        ac1 = __builtin_amdgcn_mfma_f32_16x16x32_bf16(a1_, wfr[1][1], ac1, 0,0,0); \
        ac2 = __builtin_amdgcn_mfma_f32_16x16x32_bf16(a1_, wfr[2][1], ac2, 0,0,0); \
        ac3 = __builtin_amdgcn_mfma_f32_16x16x32_bf16(a1_, wfr[3][1], ac3, 0,0,0); \
        ac0 = __builtin_amdgcn_mfma_f32_16x16x32_bf16(a2_, wfr[0][2], ac0, 0,0,0); \
        ac1 = __builtin_amdgcn_mfma_f32_16x16x32_bf16(a2_, wfr[1][2], ac1, 0,0,0); \
        ac2 = __builtin_amdgcn_mfma_f32_16x16x32_bf16(a2_, wfr[2][2], ac2, 0,0,0); \
        ac3 = __builtin_amdgcn_mfma_f32_16x16x32_bf16(a2_, wfr[3][2], ac3, 0,0,0); \
        ac0 = __builtin_amdgcn_mfma_f32_16x16x32_bf16(a3_, wfr[0][3], ac0, 0,0,0); \
        ac1 = __builtin_amdgcn_mfma_f32_16x16x32_bf16(a3_, wfr[1][3], ac1, 0,0,0); \
        ac2 = __builtin_amdgcn_mfma_f32_16x16x32_bf16(a3_, wfr[2][3], ac2, 0,0,0); \
        ac3 = __builtin_amdgcn_mfma_f32_16x16x32_bf16(a3_, wfr[3][3], ac3, 0,0,0); \
        float h0_, h1_, h2_, h3_; \
        { float iv=fast_sigmoid(ac0[0]), fv=fast_sigmoid(ac1[0]), gv=fast_tanh(ac2[0]), ov=fast_sigmoid(ac3[0]); \
          c0 = fv*c0 + iv*gv; h0_ = ov*fast_tanh(c0); } \
        { float iv=fast_sigmoid(ac0[1]), fv=fast_sigmoid(ac1[1]), gv=fast_tanh(ac2[1]), ov=fast_sigmoid(ac3[1]); \
          c1 = fv*c1 + iv*gv; h1_ = ov*fast_tanh(c1); } \
        { float iv=fast_sigmoid(ac0[2]), fv=fast_sigmoid(ac1[2]), gv=fast_tanh(ac2[2]), ov=fast_sigmoid(ac3[2]); \
          c2 = fv*c2 + iv*gv; h2_ = ov*fast_tanh(c2); } \
        { float iv=fast_sigmoid(ac0[3]), fv=fast_sigmoid(ac1[3]), gv=fast_tanh(ac2[3]), ov=fast_sigmoid(ac3[3]); \
          c3 = fv*c3 + iv*gv; h3_ = ov*fast_tanh(c3); } \
        short s0_ = f2bf(h0_), s1_ = f2bf(h1_), s2_ = f2bf(h2_), s3_ = f2bf(h3_); \
        hw0[((RB)^1)*2176      ] = s0_; \
        hw0[((RB)^1)*2176 + 136] = s1_; \
        hw0[((RB)^1)*2176 + 272] = s2_; \
        hw0[((RB)^1)*2176 + 408] = s3_; \
        __syncthreads(); \
        short* hp_ = houtbase + (long)(TT) * hstep; \
        hp_[0] = s0_; hp_[128] = s1_; hp_[256] = s2_; hp_[384] = s3_; \
    } while(0)

    for (int wnd = 0; wnd < 32; ++wnd){
        const int t0 = wnd << 3;
        LDX(B00,B01,t0+4); LDX(B10,B11,t0+5); LDX(B20,B21,t0+6); LDX(B30,B31,t0+7);
        STEPX(A00,A01,t0+0,0); STEPX(A10,A11,t0+1,1);
        STEPX(A20,A21,t0+2,0); STEPX(A30,A31,t0+3,1);
        LDX(A00,A01,t0+8); LDX(A10,A11,t0+9); LDX(A20,A21,t0+10); LDX(A30,A31,t0+11);
        STEPX(B00,B01,t0+4,0); STEPX(B10,B11,t0+5,1);
        STEPX(B20,B21,t0+6,0); STEPX(B30,B31,t0+7,1);
    }
#undef STEPX
#undef LDX
}

// ---------------------------------------------------------------------------
// Stage 3: emissions em[b][s][t] = [h_f,h_b] . w_em[t] + b_em[t]  (h is bf16)
// ---------------------------------------------------------------------------
__global__ __launch_bounds__(256) void k_em(
    const short* __restrict__ hf, const short* __restrict__ hb,
    const float* __restrict__ w_em, const float* __restrict__ b_em,
    float* __restrict__ em)
{
    __shared__ __align__(16) float HS[64][260];
    __shared__ __align__(16) float WE[9][260];
    const int tid = threadIdx.x;
    const int u0  = blockIdx.x * 64;
    const int b   = u0 >> 8;
    const int s0  = u0 & 255;

#pragma unroll
    for (int j = 0; j < 4; ++j){
        int flat = j * 256 + tid;          // 1024 chunks of 8 shorts (hf) + same (hb)
        int r = flat >> 4, ch = flat & 15;
        int s = s0 + r;
        size_t src = ((size_t)(s * 128 + b)) * 128 + ch * 8;
        bf16x8 vf = *reinterpret_cast<const bf16x8*>(hf + src);
        bf16x8 vb = *reinterpret_cast<const bf16x8*>(hb + src);
#pragma unroll
        for (int e = 0; e < 8; ++e){
            HS[r][ch * 8 + e]       = bf2f(vf[e]);
            HS[r][128 + ch * 8 + e] = bf2f(vb[e]);
        }
    }
    for (int j = tid; j < 9 * 256; j += 256){
        int tt = j >> 8, k = j & 255;
        WE[tt][k] = w_em[j];
    }
    __syncthreads();

    const int tok = tid >> 2, tq = tid & 3;
    const float4* hrow = reinterpret_cast<const float4*>(&HS[tok][0]);
    for (int rep = 0; rep < 3; ++rep){
        if (rep == 2 && tq != 0) break;
        int tt = (rep == 0) ? tq : (rep == 1 ? tq + 4 : 8);
        const float4* wrow4 = reinterpret_cast<const float4*>(&WE[tt][0]);
        float acc = b_em[tt];
#pragma unroll
        for (int k4 = 0; k4 < 64; ++k4){
            float4 h4 = hrow[k4];
            float4 w4 = wrow4[k4];
            acc += h4.x*w4.x; acc += h4.y*w4.y; acc += h4.z*w4.z; acc += h4.w*w4.w;
        }
        em[(size_t)(u0 + tok) * 9 + tt] = acc;
    }
}

// ---------------------------------------------------------------------------
// Stage 4: CRF per-batch NLL (1 wave per b), then mean.
// ---------------------------------------------------------------------------
__global__ __launch_bounds__(64) void k_crf(
    const float* __restrict__ em, const int* __restrict__ tags,
    const float* __restrict__ start_t, const float* __restrict__ end_t,
    const float* __restrict__ trans, float* __restrict__ perb)
{
    const int b = blockIdx.x;
    const int l = threadIdx.x;
    const int base = b * 256;

    float sc = 0.0f;
    for (int s = l; s < 256; s += 64){
        int tg = tags[base + s];
        sc += em[(size_t)(base + s) * 9 + tg];
        if (s < 255) sc += trans[tg * 9 + tags[base + s + 1]];
    }
#pragma unroll
    for (int off = 32; off > 0; off >>= 1) sc += __shfl_down(sc, off);

    float alpha = -1e30f, endt = 0.0f;
    float m[9];
#pragma unroll
    for (int i = 0; i < 9; ++i) m[i] = 0.0f;
    if (l < 9){
#pragma unroll
        for (int i = 0; i < 9; ++i) m[i] = exp2f(trans[i * 9 + l] * L2E);
        alpha = start_t[l] + em[(size_t)base * 9 + l];
        endt  = end_t[l];
    }
    float emv = (l < 9) ? em[(size_t)(base + 1) * 9 + l] : 0.0f;
    for (int s = 1; s < 256; ++s){
        float emn = (s < 255 && l < 9) ? em[(size_t)(base + s + 1) * 9 + l] : 0.0f;
        float a0 = __shfl(alpha, 0);
        float e  = exp2f((alpha - a0) * L2E);
        float ssum = 0.0f;
#pragma unroll
        for (int i = 0; i < 9; ++i) ssum += __shfl(e, i) * m[i];
        alpha = a0 + log2f(ssum) * LN2 + emv;
        emv = emn;
    }
    float v  = (l < 9) ? alpha + endt : -1e30f;
    float mx = v;
#pragma unroll
    for (int off = 32; off > 0; off >>= 1) mx = fmaxf(mx, __shfl_xor(mx, off));
    float ex = (l < 9) ? exp2f((v - mx) * L2E) : 0.0f;
#pragma unroll
    for (int off = 32; off > 0; off >>= 1) ex += __shfl_xor(ex, off);
    float logz = mx + log2f(ex) * LN2;
    if (l == 0){
        float score = sc + start_t[tags[base]] + end_t[tags[base + 255]];
        perb[b] = logz - score;
    }
}

__global__ __launch_bounds__(64) void k_final(const float* __restrict__ perb,
                                              float* __restrict__ out)
{
    const int l = threadIdx.x;
    float v = perb[l] + perb[l + 64];
#pragma unroll
    for (int off = 32; off > 0; off >>= 1) v += __shfl_down(v, off);
    if (l == 0) out[0] = v * (1.0f / 128.0f);
}

// ---------------------------------------------------------------------------
extern "C" void kernel_launch(void* const* d_in, const int* in_sizes, int n_in,
                              void* d_out, int out_size, void* d_ws, size_t ws_size,
                              hipStream_t stream)
{
    (void)in_sizes; (void)n_in; (void)out_size; (void)ws_size;
    const int*   ids   = (const int*)d_in[0];
    const int*   tags  = (const int*)d_in[1];
    const float* embed = (const float*)d_in[2];
    const float* wif   = (const float*)d_in[3];
    const float* whf   = (const float*)d_in[4];
    const float* bif   = (const float*)d_in[5];
    const float* bhf   = (const float*)d_in[6];
    const float* wib   = (const float*)d_in[7];
    const float* whb   = (const float*)d_in[8];
    const float* bib   = (const float*)d_in[9];
    const float* bhb   = (const float*)d_in[10];
    const float* w_em  = (const float*)d_in[11];
    const float* b_em  = (const float*)d_in[12];
    const float* st    = (const float*)d_in[13];
    const float* et    = (const float*)d_in[14];
    const float* tr    = (const float*)d_in[15];
    float* out = (float*)d_out;

    char* p = (char*)d_ws;
    short* xp2  = (short*)p;                       // 67,108,864 B
    short* hf   = (short*)(p + 67108864);          //  8,388,608 B
    short* hb   = (short*)(p + 75497472);          //  8,388,608 B
    float* em   = (float*)(p + 83886080);          //  1,179,648 B
    float* perb = (float*)(p + 85065728);          //        512 B

    k_xproj<<<dim3(256), dim3(512), 0, stream>>>(ids, embed, wif, bif, bhf,
                                                 wib, bib, bhb, xp2);
    k_scan <<<dim3(16),  dim3(512), 0, stream>>>(xp2, whf, whb, hf, hb);
    k_em   <<<dim3(512), dim3(256), 0, stream>>>(hf, hb, w_em, b_em, em);
    k_crf  <<<dim3(128), dim3(64),  0, stream>>>(em, tags, st, et, tr, perb);
    k_final<<<dim3(1),   dim3(64),  0, stream>>>(perb, out);
}